// Round 4
// baseline (927.452 us; speedup 1.0000x reference)
//
#include <hip/hip_runtime.h>
#include <hip/hip_bf16.h>

// ModulatedConv2d: B=8, Cin=Cout=512, K=3, H=W=64, pad=1, groups=B.
// bf16 MFMA implicit GEMM per batch: C[512,4096] = Wmod[512,4608] x Im2col.
// R10 DIAGNOSTIC ROUND: main pipeline identical to R9 (8-phase 256x256,
// counted vmcnt(6), sched_barrier pins; 168us, MfmaUtil 38%). Two theory
// misses in a row -> m233-style ablation. Three diag dispatches (workspace-
// only writes, after conv_gemm; correctness unaffected):
//   conv_diag<1,80> NOSTAGE: no staging/vmcnt in loop -> reads+barriers+MFMA
//   conv_diag<2,80> NOREAD : no ds_reads in loop -> stage+vmcnt+barriers+MFMA
//   conv_diag<3,56> NOBAR  : no s_barriers -> reads+stage+vmcnt+MFMA
// Compare per-iter vs main's 4.7us/iter; absence from top-5 => that
// component >= ~40-55% of phase time.

#define CIN   512
#define COUT  512
#define KDIM  4608        // 9 * 512
#define HWPIX 4096

typedef __attribute__((ext_vector_type(8))) __bf16 bf16x8;
typedef __attribute__((ext_vector_type(4))) float  f32x4;

__device__ __forceinline__ unsigned short f2bf(float f){
  union { float f; unsigned int u; } v; v.f = f;
  unsigned int u = v.u;
  u += 0x7fffu + ((u >> 16) & 1u);     // round-to-nearest-even
  return (unsigned short)(u >> 16);
}

#define GLDS16(g, l) __builtin_amdgcn_global_load_lds(                      \
    (const __attribute__((address_space(1))) unsigned int*)(g),             \
    (__attribute__((address_space(3))) unsigned int*)(l), 16, 0, 0)

// ---------------- styles: s[b][c] = dot(w[b], affine_w[c]) + ab[c] + 1 ----
__global__ void style_k(const float* __restrict__ w, const float* __restrict__ aw,
                        const float* __restrict__ ab, float* __restrict__ styles){
  int wid = threadIdx.x >> 6, lane = threadIdx.x & 63;
  int gid = blockIdx.x * 4 + wid;           // 0..4095 = b*512 + c
  int b = gid >> 9, c = gid & 511;
  const float* wb = w + b * 512;
  const float* ar = aw + c * 512;
  float sum = 0.f;
  for (int j = lane; j < 512; j += 64) sum += wb[j] * ar[j];
  for (int off = 32; off; off >>= 1) sum += __shfl_down(sum, off, 64);
  if (lane == 0) styles[gid] = sum + ab[c] + 1.0f;
}

// ------------- modulate + demodulate -> bf16 wmod[b][o][tap*512+cin] ------
__global__ void modw_k(const float* __restrict__ weight, const float* __restrict__ styles,
                       unsigned short* __restrict__ wmod){
  int o = blockIdx.x;                  // 0..511
  int b = blockIdx.y;                  // 0..7
  int t = threadIdx.x;
  const float* wrow = weight + (size_t)o * KDIM;   // weight[0][o][i][ky][kx]
  const float* st = styles + b * 512;
  __shared__ unsigned short sw[9 * 520];           // tap stride 520 (pad vs 512)
  __shared__ float red[4];
  int wid = t >> 6, lane = t & 63;
  float vals[18];
  float part = 0.f;
#pragma unroll
  for (int it = 0; it < 9; ++it){
    int e = (it * 256 + t) * 2;
    float2 v2 = *(const float2*)(wrow + e);
    int i0 = e / 9, i1 = (e + 1) / 9;
    float a0 = v2.x * st[i0];
    float a1 = v2.y * st[i1];
    vals[2 * it] = a0; vals[2 * it + 1] = a1;
    part += a0 * a0 + a1 * a1;
  }
  for (int off = 32; off; off >>= 1) part += __shfl_down(part, off, 64);
  if (lane == 0) red[wid] = part;
  __syncthreads();
  float d = rsqrtf(red[0] + red[1] + red[2] + red[3] + 1e-8f);
#pragma unroll
  for (int it = 0; it < 9; ++it){
    int e = (it * 256 + t) * 2;
    int i0 = e / 9, i1 = (e + 1) / 9;
    int tap0 = e - i0 * 9, tap1 = e + 1 - i1 * 9;
    sw[tap0 * 520 + i0] = f2bf(vals[2 * it] * d);
    sw[tap1 * 520 + i1] = f2bf(vals[2 * it + 1] * d);
  }
  __syncthreads();
  unsigned int* orow32 = (unsigned int*)(wmod + ((size_t)(b * 512 + o)) * KDIM);
#pragma unroll
  for (int it = 0; it < 9; ++it){     // 2304 dwords, fully coalesced
    int u = it * 256 + t;
    int e = u * 2;
    int tap2 = e >> 9, i2 = e & 511;
    orow32[u] = *(const unsigned int*)&sw[tap2 * 520 + i2];
  }
}

// ----- transpose+pad: x[b][c][h][w] fp32 -> xpad[b][h+1][w+1][c] bf16 -----
__global__ void xpose_k(const float* __restrict__ x, unsigned short* __restrict__ xpad){
  int h = blockIdx.x, cg = blockIdx.y, b = blockIdx.z;
  int c0 = cg * 64;
  __shared__ unsigned short lds[64][66];   // [w][c]
  int t = threadIdx.x;
  const float* xb = x + (((size_t)(b * 512 + c0)) * 64 + h) * 64;
#pragma unroll
  for (int it = 0; it < 4; ++it){
    int idx = it * 256 + t;                // 0..1023
    int cl = idx >> 4, w4 = (idx & 15) * 4;
    float4 v = *(const float4*)(xb + (size_t)cl * 4096 + w4);
    lds[w4 + 0][cl] = f2bf(v.x);
    lds[w4 + 1][cl] = f2bf(v.y);
    lds[w4 + 2][cl] = f2bf(v.z);
    lds[w4 + 3][cl] = f2bf(v.w);
  }
  if (t < 64){
    int which = t >> 5;                   // 0: w=0, 1: w=65
    int ch2 = (t & 31) * 2;
    int wl = which ? 65 : 0;
    *(unsigned int*)&xpad[(((size_t)b * 66 + h + 1) * 66 + wl) * 512 + c0 + ch2] = 0u;
  }
  if (h == 0 || h == 63){                 // rows 0 / 65, all 66 w
    int row = (h == 0) ? 0 : 65;
    for (int u = t; u < 66 * 32; u += 256){
      int wl = u >> 5, ch2 = (u & 31) * 2;
      *(unsigned int*)&xpad[(((size_t)b * 66 + row) * 66 + wl) * 512 + c0 + ch2] = 0u;
    }
  }
  __syncthreads();
#pragma unroll
  for (int it = 0; it < 2; ++it){
    int idx = it * 256 + t;
    int wl = idx >> 3, ch = idx & 7;
    unsigned int u0 = *(const unsigned int*)&lds[wl][ch * 8 + 0];
    unsigned int u1 = *(const unsigned int*)&lds[wl][ch * 8 + 2];
    unsigned int u2 = *(const unsigned int*)&lds[wl][ch * 8 + 4];
    unsigned int u3 = *(const unsigned int*)&lds[wl][ch * 8 + 6];
    int off = ((b * 66 + h + 1) * 66 + (wl + 1)) * 512 + c0 + ch * 8;
    *(uint4*)&xpad[off] = make_uint4(u0, u1, u2, u3);
  }
}

// --------------------------- main conv GEMM ------------------------------
__device__ __forceinline__ int bshift_of(int t){
  int tap = t >> 3;
  int dy = (tap * 11) >> 5;              // tap/3 for tap in [0,9)
  int dx = tap - dy * 3;
  return (((dy - 1) * 66 + (dx - 1)) << 9) + ((t & 7) << 6);
}

__global__ __launch_bounds__(512, 2) void conv_gemm(
    const unsigned short* __restrict__ wmod, const unsigned short* __restrict__ xpad,
    const float* __restrict__ noise, const float* __restrict__ bias,
    float* __restrict__ out){
  __shared__ unsigned short As[4][128 * 64];   // 64 KiB
  __shared__ unsigned short Bs[4][128 * 64];   // 64 KiB
  int g = blockIdx.x;                          // 256 blocks: 1 per CU
  int b = g & 7, sl = g >> 3;                  // b == XCD
  int mt = sl >> 4, nt = sl & 15;
  int m0 = mt * 256, n0 = nt * 256, h0 = nt * 4;
  int tid = threadIdx.x, lane = tid & 63, wid = tid >> 6;
  int wmp = wid >> 2, wnp = wid & 3;
  int lf = lane & 15, lg = lane >> 4;

  const unsigned short* wbase = wmod + ((size_t)(b * 512 + m0)) * KDIM;
  const unsigned short* xb    = xpad + (size_t)b * (66 * 66 * 512);

  int srow  = tid >> 3;
  int sc    = (tid & 7) ^ (srow & 7);
  int aoffg  = srow * KDIM + sc * 8;
  int boffg0 = ((h0 + 1) * 66 + srow + 1) * 512 + sc * 8;
  int boffg1 = ((h0 + 2) * 66 + srow + 1) * 512 + sc * 8;

  int arow[4], brow[2];
#pragma unroll
  for (int i = 0; i < 4; ++i) arow[i] = (wmp * 64 + i * 16 + lf) * 64;
#pragma unroll
  for (int j = 0; j < 2; ++j) brow[j] = (wnp * 32 + j * 16 + lf) * 64;
  int pch0 = ((lg    ) ^ (lane & 7)) * 8;
  int pch1 = ((lg + 4) ^ (lane & 7)) * 8;

  f32x4 acc[2][2][4][2];
#pragma unroll
  for (int a0 = 0; a0 < 2; ++a0)
#pragma unroll
    for (int a1 = 0; a1 < 2; ++a1)
#pragma unroll
      for (int a2 = 0; a2 < 4; ++a2)
#pragma unroll
        for (int a3 = 0; a3 < 2; ++a3) acc[a0][a1][a2][a3] = (f32x4){0.f, 0.f, 0.f, 0.f};

  bf16x8 af[4][2], bq0[2][2], bq1[2][2];

#define SBAR0() __builtin_amdgcn_sched_barrier(0)

#define STAGE_A(t_, h_, s_) do {                                              \
    const unsigned short* gpa_ = wbase + (size_t)(h_) * (128 * KDIM) + (t_) * 64; \
    GLDS16(gpa_ + aoffg,             &As[s_][tid * 8]);                       \
    GLDS16(gpa_ + aoffg + 64 * KDIM, &As[s_][(512 + tid) * 8]);               \
  } while (0)

#define STAGE_B(t_, h_, s_) do {                                              \
    const unsigned short* gpb_ = xb + (h_) * (2 * 66 * 512) + bshift_of(t_);  \
    GLDS16(gpb_ + boffg0, &Bs[s_][tid * 8]);                                  \
    GLDS16(gpb_ + boffg1, &Bs[s_][(512 + tid) * 8]);                          \
  } while (0)

#define LOAD_A(s_) do {                                                       \
    _Pragma("unroll") for (int fi_ = 0; fi_ < 4; ++fi_){                      \
      af[fi_][0] = *(const bf16x8*)&As[s_][arow[fi_] + pch0];                 \
      af[fi_][1] = *(const bf16x8*)&As[s_][arow[fi_] + pch1]; }               \
  } while (0)

#define LOAD_B(s_, B_) do {                                                   \
    _Pragma("unroll") for (int fj_ = 0; fj_ < 2; ++fj_){                      \
      B_[fj_][0] = *(const bf16x8*)&Bs[s_][brow[fj_] + pch0];                 \
      B_[fj_][1] = *(const bf16x8*)&Bs[s_][brow[fj_] + pch1]; }               \
  } while (0)

#define MFMA_Q(MH_, NH_, B_) do {                                             \
    __builtin_amdgcn_s_setprio(1);                                            \
    _Pragma("unroll") for (int fi_ = 0; fi_ < 4; ++fi_)                       \
    _Pragma("unroll") for (int fj_ = 0; fj_ < 2; ++fj_){                      \
      acc[MH_][NH_][fi_][fj_] = __builtin_amdgcn_mfma_f32_16x16x32_bf16(      \
          af[fi_][0], B_[fj_][0], acc[MH_][NH_][fi_][fj_], 0, 0, 0);          \
      acc[MH_][NH_][fi_][fj_] = __builtin_amdgcn_mfma_f32_16x16x32_bf16(      \
          af[fi_][1], B_[fj_][1], acc[MH_][NH_][fi_][fj_], 0, 0, 0); }        \
    __builtin_amdgcn_s_setprio(0);                                            \
  } while (0)

#define SYNC_MID() do { SBAR0(); __builtin_amdgcn_s_barrier();                \
    asm volatile("s_waitcnt lgkmcnt(0)" ::: "memory"); SBAR0(); } while (0)
#define SYNC_END() do { SBAR0(); __builtin_amdgcn_s_barrier(); } while (0)
#define VMW6() asm volatile("s_waitcnt vmcnt(6)" ::: "memory")
#define VMW0() asm volatile("s_waitcnt vmcnt(0)" ::: "memory")

  STAGE_A(0, 0, 0); STAGE_B(0, 0, 0); STAGE_B(0, 1, 1); STAGE_A(0, 1, 1);
  STAGE_A(1, 0, 2); STAGE_B(1, 0, 2); STAGE_B(1, 1, 3);
  VMW6();
  __builtin_amdgcn_s_barrier();

#pragma unroll 1
  for (int it = 0; it < 35; ++it){
    int T = it * 2;
    LOAD_A(0); LOAD_B(0, bq0);
    STAGE_A(T + 1, 1, 3);
    SYNC_MID(); MFMA_Q(0, 0, bq0); SYNC_END();
    LOAD_B(1, bq1);
    STAGE_A(T + 2, 0, 0);
    SYNC_MID(); MFMA_Q(0, 1, bq1); SYNC_END();
    LOAD_A(1);
    STAGE_B(T + 2, 0, 0);
    SYNC_MID(); MFMA_Q(1, 0, bq0); SYNC_END();
    STAGE_B(T + 2, 1, 1);
    VMW6();
    SYNC_MID(); MFMA_Q(1, 1, bq1); SYNC_END();
    LOAD_A(2); LOAD_B(2, bq0);
    STAGE_A(T + 2, 1, 1);
    SYNC_MID(); MFMA_Q(0, 0, bq0); SYNC_END();
    LOAD_B(3, bq1);
    STAGE_A(T + 3, 0, 2);
    SYNC_MID(); MFMA_Q(0, 1, bq1); SYNC_END();
    LOAD_A(3);
    STAGE_B(T + 3, 0, 2);
    SYNC_MID(); MFMA_Q(1, 0, bq0); SYNC_END();
    STAGE_B(T + 3, 1, 3);
    VMW6();
    SYNC_MID(); MFMA_Q(1, 1, bq1); SYNC_END();
  }

  LOAD_A(0); LOAD_B(0, bq0);
  STAGE_A(71, 1, 3);
  SYNC_MID(); MFMA_Q(0, 0, bq0); SYNC_END();
  LOAD_B(1, bq1);
  SYNC_MID(); MFMA_Q(0, 1, bq1); SYNC_END();
  LOAD_A(1);
  SYNC_MID(); MFMA_Q(1, 0, bq0); SYNC_END();
  VMW0();
  SYNC_MID(); MFMA_Q(1, 1, bq1); SYNC_END();
  LOAD_A(2); LOAD_B(2, bq0);
  SYNC_MID(); MFMA_Q(0, 0, bq0); SYNC_END();
  LOAD_B(3, bq1);
  SYNC_MID(); MFMA_Q(0, 1, bq1); SYNC_END();
  LOAD_A(3);
  SYNC_MID(); MFMA_Q(1, 0, bq0); SYNC_END();
  SYNC_MID(); MFMA_Q(1, 1, bq1);

  // epilogue: + noise + bias, leaky relu 0.2
#pragma unroll
  for (int MH = 0; MH < 2; ++MH)
#pragma unroll
    for (int NH = 0; NH < 2; ++NH)
#pragma unroll
      for (int fi = 0; fi < 4; ++fi)
#pragma unroll
        for (int fj = 0; fj < 2; ++fj){
          int o_base = m0 + MH * 128 + wmp * 64 + fi * 16 + lg * 4;
          int n = n0 + NH * 128 + wnp * 32 + fj * 16 + lf;
#pragma unroll
          for (int r = 0; r < 4; ++r){
            int o = o_base + r;
            size_t idx = ((size_t)(b * 512 + o)) * HWPIX + n;
            float v = acc[MH][NH][fi][fj][r] + noise[idx] + bias[o];
            out[idx] = (v >= 0.f) ? v : 0.2f * v;
          }
        }
}

// --------------------------- diagnostics ---------------------------------
// VAR 1 = NOSTAGE (no staging/vmcnt in loop), 2 = NOREAD (no ds_reads in
// loop), 3 = NOBAR (no s_barriers). Write digest to workspace only.
__device__ __forceinline__ int wrap72(int t){
  t -= (t >= 72) ? 72 : 0;
  t -= (t >= 72) ? 72 : 0;
  return t;
}

template<int VAR, int ITERS>
__global__ __launch_bounds__(512, 2) void conv_diag(
    const unsigned short* __restrict__ wmod, const unsigned short* __restrict__ xpad,
    float* __restrict__ scratch){
  __shared__ unsigned short As[4][128 * 64];
  __shared__ unsigned short Bs[4][128 * 64];
  int g = blockIdx.x;
  int b = g & 7, sl = g >> 3;
  int mt = sl >> 4, nt = sl & 15;
  int m0 = mt * 256, h0 = nt * 4;
  int tid = threadIdx.x, lane = tid & 63, wid = tid >> 6;
  int wmp = wid >> 2, wnp = wid & 3;
  int lf = lane & 15, lg = lane >> 4;

  const unsigned short* wbase = wmod + ((size_t)(b * 512 + m0)) * KDIM;
  const unsigned short* xb    = xpad + (size_t)b * (66 * 66 * 512);

  int srow  = tid >> 3;
  int sc    = (tid & 7) ^ (srow & 7);
  int aoffg  = srow * KDIM + sc * 8;
  int boffg0 = ((h0 + 1) * 66 + srow + 1) * 512 + sc * 8;
  int boffg1 = ((h0 + 2) * 66 + srow + 1) * 512 + sc * 8;

  int arow[4], brow[2];
#pragma unroll
  for (int i = 0; i < 4; ++i) arow[i] = (wmp * 64 + i * 16 + lf) * 64;
#pragma unroll
  for (int j = 0; j < 2; ++j) brow[j] = (wnp * 32 + j * 16 + lf) * 64;
  int pch0 = ((lg    ) ^ (lane & 7)) * 8;
  int pch1 = ((lg + 4) ^ (lane & 7)) * 8;

  f32x4 acc[2][2][4][2];
#pragma unroll
  for (int a0 = 0; a0 < 2; ++a0)
#pragma unroll
    for (int a1 = 0; a1 < 2; ++a1)
#pragma unroll
      for (int a2 = 0; a2 < 4; ++a2)
#pragma unroll
        for (int a3 = 0; a3 < 2; ++a3) acc[a0][a1][a2][a3] = (f32x4){0.f, 0.f, 0.f, 0.f};

  bf16x8 af[4][2], bq0[2][2], bq1[2][2];

  // prologue: stage all slots, drain, one barrier; preload frags for NOREAD
  STAGE_A(0, 0, 0); STAGE_B(0, 0, 0); STAGE_B(0, 1, 1); STAGE_A(0, 1, 1);
  STAGE_A(1, 0, 2); STAGE_B(1, 0, 2); STAGE_B(1, 1, 3);
  VMW0();
  __builtin_amdgcn_s_barrier();
  LOAD_A(0); LOAD_B(0, bq0); LOAD_B(1, bq1);
  asm volatile("s_waitcnt lgkmcnt(0)" ::: "memory");

#define D_SM() do { if constexpr (VAR != 3) { SBAR0();                        \
      __builtin_amdgcn_s_barrier();                                           \
      asm volatile("s_waitcnt lgkmcnt(0)" ::: "memory"); SBAR0(); }           \
    else { SBAR0();                                                           \
      asm volatile("s_waitcnt lgkmcnt(0)" ::: "memory"); SBAR0(); } } while (0)
#define D_SE() do { if constexpr (VAR != 3) { SBAR0();                        \
      __builtin_amdgcn_s_barrier(); } else { SBAR0(); } } while (0)

#pragma unroll 1
  for (int it = 0; it < ITERS; ++it){
    int T = it * 2;
    int w1 = wrap72(T + 1), w2 = wrap72(T + 2), w3 = wrap72(T + 3);
    // P1
    if constexpr (VAR != 2) { LOAD_A(0); LOAD_B(0, bq0); }
    if constexpr (VAR != 1) STAGE_A(w1, 1, 3);
    D_SM(); MFMA_Q(0, 0, bq0); D_SE();
    // P2
    if constexpr (VAR != 2) LOAD_B(1, bq1);
    if constexpr (VAR != 1) STAGE_A(w2, 0, 0);
    D_SM(); MFMA_Q(0, 1, bq1); D_SE();
    // P3
    if constexpr (VAR != 2) LOAD_A(1);
    if constexpr (VAR != 1) STAGE_B(w2, 0, 0);
    D_SM(); MFMA_Q(1, 0, bq0); D_SE();
    // P4
    if constexpr (VAR != 1) { STAGE_B(w2, 1, 1); VMW6(); }
    D_SM(); MFMA_Q(1, 1, bq1); D_SE();
    // P5
    if constexpr (VAR != 2) { LOAD_A(2); LOAD_B(2, bq0); }
    if constexpr (VAR != 1) STAGE_A(w2, 1, 1);
    D_SM(); MFMA_Q(0, 0, bq0); D_SE();
    // P6
    if constexpr (VAR != 2) LOAD_B(3, bq1);
    if constexpr (VAR != 1) STAGE_A(w3, 0, 2);
    D_SM(); MFMA_Q(0, 1, bq1); D_SE();
    // P7
    if constexpr (VAR != 2) LOAD_A(3);
    if constexpr (VAR != 1) STAGE_B(w3, 0, 2);
    D_SM(); MFMA_Q(1, 0, bq0); D_SE();
    // P8
    if constexpr (VAR != 1) { STAGE_B(w3, 1, 3); VMW6(); }
    D_SM(); MFMA_Q(1, 1, bq1); D_SE();
  }
  if constexpr (VAR != 1) VMW0();

  // digest (keeps everything live); workspace-only write
  float s = 0.f;
#pragma unroll
  for (int a0 = 0; a0 < 2; ++a0)
#pragma unroll
    for (int a1 = 0; a1 < 2; ++a1)
#pragma unroll
      for (int a2 = 0; a2 < 4; ++a2)
#pragma unroll
        for (int a3 = 0; a3 < 2; ++a3)
#pragma unroll
          for (int r = 0; r < 4; ++r) s += acc[a0][a1][a2][a3][r];
  scratch[(g * 512 + tid) & 4095] = s;
#undef D_SM
#undef D_SE
}

#undef STAGE_A
#undef STAGE_B
#undef LOAD_A
#undef LOAD_B
#undef MFMA_Q
#undef SYNC_MID
#undef SYNC_END
#undef VMW6
#undef VMW0
#undef SBAR0

extern "C" void kernel_launch(void* const* d_in, const int* in_sizes, int n_in,
                              void* d_out, int out_size, void* d_ws, size_t ws_size,
                              hipStream_t stream) {
  const float* x        = (const float*)d_in[0];
  const float* w        = (const float*)d_in[1];
  const float* noise    = (const float*)d_in[2];
  const float* weight   = (const float*)d_in[3];
  const float* affine_w = (const float*)d_in[4];
  const float* affine_b = (const float*)d_in[5];
  const float* bias     = (const float*)d_in[6];
  float* out = (float*)d_out;

  // workspace: styles 16KB | wmod 37,748,736B | xpad 35,684,352B  (~73.5 MB)
  float* styles = (float*)d_ws;
  unsigned short* wmod = (unsigned short*)((char*)d_ws + 16384);
  unsigned short* xpad = (unsigned short*)((char*)d_ws + 16384 + 37748736ull);

  style_k<<<dim3(1024), 256, 0, stream>>>(w, affine_w, affine_b, styles);
  modw_k <<<dim3(512, 8), 256, 0, stream>>>(weight, styles, wmod);
  xpose_k<<<dim3(64, 8, 8), 256, 0, stream>>>(x, xpad);
  conv_gemm<<<dim3(256), 512, 0, stream>>>(wmod, xpad, noise, bias, out);
  // diagnostics (workspace-only; output already written; replay regenerates
  // wmod/xpad before conv_gemm each iteration)
  conv_diag<1, 80><<<dim3(256), 512, 0, stream>>>(wmod, xpad, (float*)d_ws);
  conv_diag<2, 80><<<dim3(256), 512, 0, stream>>>(wmod, xpad, (float*)d_ws);
  conv_diag<3, 56><<<dim3(256), 512, 0, stream>>>(wmod, xpad, (float*)d_ws);
}

// Round 7
// 338.013 us; speedup vs baseline: 2.7438x; 2.7438x over previous
//
#include <hip/hip_runtime.h>
#include <hip/hip_bf16.h>

// ModulatedConv2d: B=8, Cin=Cout=512, K=3, H=W=64, pad=1, groups=B.
// bf16 MFMA implicit GEMM per batch: C[512,4096] = Wmod[512,4608] x Im2col.
// R11 (2nd resubmit; R5 and R6 benches were broker timeouts, never measured):
// ablation (R10) showed the 2-barrier/phase lockstep serializes the LDS
// pipe and matrix pipe (NOBAR ~2.3-2.9us/iter, NOSTAGE 3.0, main 4.68 -> costs
// non-additive). Restructure: ONE barrier per phase; ds_reads issue one phase
// AHEAD of use (6/phase uniform, counted lgkmcnt(6) head wait); stages at
// Q2(A0+B0),Q3(B1),Q4(A1),Q6(A2+B2),Q7(B3),Q8(A3); vmcnt(4) at Q4/Q8 only.
// Ledger verified: every stage retires a VMW + barrier before its first read;
// every overwrite is >=1 barrier after the lgkm that completes old reads.
// Now each phase's MFMA cluster covers its (future-operand) ds_reads ->
// LDS and matrix pipes overlap instead of alternating.

#define CIN   512
#define COUT  512
#define KDIM  4608        // 9 * 512
#define HWPIX 4096

typedef __attribute__((ext_vector_type(8))) __bf16 bf16x8;
typedef __attribute__((ext_vector_type(4))) float  f32x4;

__device__ __forceinline__ unsigned short f2bf(float f){
  union { float f; unsigned int u; } v; v.f = f;
  unsigned int u = v.u;
  u += 0x7fffu + ((u >> 16) & 1u);     // round-to-nearest-even
  return (unsigned short)(u >> 16);
}

#define GLDS16(g, l) __builtin_amdgcn_global_load_lds(                      \
    (const __attribute__((address_space(1))) unsigned int*)(g),             \
    (__attribute__((address_space(3))) unsigned int*)(l), 16, 0, 0)

// ---------------- styles: s[b][c] = dot(w[b], affine_w[c]) + ab[c] + 1 ----
__global__ void style_k(const float* __restrict__ w, const float* __restrict__ aw,
                        const float* __restrict__ ab, float* __restrict__ styles){
  int wid = threadIdx.x >> 6, lane = threadIdx.x & 63;
  int gid = blockIdx.x * 4 + wid;           // 0..4095 = b*512 + c
  int b = gid >> 9, c = gid & 511;
  const float* wb = w + b * 512;
  const float* ar = aw + c * 512;
  float sum = 0.f;
  for (int j = lane; j < 512; j += 64) sum += wb[j] * ar[j];
  for (int off = 32; off; off >>= 1) sum += __shfl_down(sum, off, 64);
  if (lane == 0) styles[gid] = sum + ab[c] + 1.0f;
}

// ------------- modulate + demodulate -> bf16 wmod[b][o][tap*512+cin] ------
__global__ void modw_k(const float* __restrict__ weight, const float* __restrict__ styles,
                       unsigned short* __restrict__ wmod){
  int o = blockIdx.x;                  // 0..511
  int b = blockIdx.y;                  // 0..7
  int t = threadIdx.x;
  const float* wrow = weight + (size_t)o * KDIM;   // weight[0][o][i][ky][kx]
  const float* st = styles + b * 512;
  __shared__ unsigned short sw[9 * 520];           // tap stride 520 (pad vs 512)
  __shared__ float red[4];
  int wid = t >> 6, lane = t & 63;
  float vals[18];
  float part = 0.f;
#pragma unroll
  for (int it = 0; it < 9; ++it){
    int e = (it * 256 + t) * 2;
    float2 v2 = *(const float2*)(wrow + e);
    int i0 = e / 9, i1 = (e + 1) / 9;
    float a0 = v2.x * st[i0];
    float a1 = v2.y * st[i1];
    vals[2 * it] = a0; vals[2 * it + 1] = a1;
    part += a0 * a0 + a1 * a1;
  }
  for (int off = 32; off; off >>= 1) part += __shfl_down(part, off, 64);
  if (lane == 0) red[wid] = part;
  __syncthreads();
  float d = rsqrtf(red[0] + red[1] + red[2] + red[3] + 1e-8f);
#pragma unroll
  for (int it = 0; it < 9; ++it){
    int e = (it * 256 + t) * 2;
    int i0 = e / 9, i1 = (e + 1) / 9;
    int tap0 = e - i0 * 9, tap1 = e + 1 - i1 * 9;
    sw[tap0 * 520 + i0] = f2bf(vals[2 * it] * d);
    sw[tap1 * 520 + i1] = f2bf(vals[2 * it + 1] * d);
  }
  __syncthreads();
  unsigned int* orow32 = (unsigned int*)(wmod + ((size_t)(b * 512 + o)) * KDIM);
#pragma unroll
  for (int it = 0; it < 9; ++it){     // 2304 dwords, fully coalesced
    int u = it * 256 + t;
    int e = u * 2;
    int tap2 = e >> 9, i2 = e & 511;
    orow32[u] = *(const unsigned int*)&sw[tap2 * 520 + i2];
  }
}

// ----- transpose+pad: x[b][c][h][w] fp32 -> xpad[b][h+1][w+1][c] bf16 -----
__global__ void xpose_k(const float* __restrict__ x, unsigned short* __restrict__ xpad){
  int h = blockIdx.x, cg = blockIdx.y, b = blockIdx.z;
  int c0 = cg * 64;
  __shared__ unsigned short lds[64][66];   // [w][c]
  int t = threadIdx.x;
  const float* xb = x + (((size_t)(b * 512 + c0)) * 64 + h) * 64;
#pragma unroll
  for (int it = 0; it < 4; ++it){
    int idx = it * 256 + t;                // 0..1023
    int cl = idx >> 4, w4 = (idx & 15) * 4;
    float4 v = *(const float4*)(xb + (size_t)cl * 4096 + w4);
    lds[w4 + 0][cl] = f2bf(v.x);
    lds[w4 + 1][cl] = f2bf(v.y);
    lds[w4 + 2][cl] = f2bf(v.z);
    lds[w4 + 3][cl] = f2bf(v.w);
  }
  if (t < 64){
    int which = t >> 5;                   // 0: w=0, 1: w=65
    int ch2 = (t & 31) * 2;
    int wl = which ? 65 : 0;
    *(unsigned int*)&xpad[(((size_t)b * 66 + h + 1) * 66 + wl) * 512 + c0 + ch2] = 0u;
  }
  if (h == 0 || h == 63){                 // rows 0 / 65, all 66 w
    int row = (h == 0) ? 0 : 65;
    for (int u = t; u < 66 * 32; u += 256){
      int wl = u >> 5, ch2 = (u & 31) * 2;
      *(unsigned int*)&xpad[(((size_t)b * 66 + row) * 66 + wl) * 512 + c0 + ch2] = 0u;
    }
  }
  __syncthreads();
#pragma unroll
  for (int it = 0; it < 2; ++it){
    int idx = it * 256 + t;
    int wl = idx >> 3, ch = idx & 7;
    unsigned int u0 = *(const unsigned int*)&lds[wl][ch * 8 + 0];
    unsigned int u1 = *(const unsigned int*)&lds[wl][ch * 8 + 2];
    unsigned int u2 = *(const unsigned int*)&lds[wl][ch * 8 + 4];
    unsigned int u3 = *(const unsigned int*)&lds[wl][ch * 8 + 6];
    int off = ((b * 66 + h + 1) * 66 + (wl + 1)) * 512 + c0 + ch * 8;
    *(uint4*)&xpad[off] = make_uint4(u0, u1, u2, u3);
  }
}

// --------------------------- main conv GEMM ------------------------------
__device__ __forceinline__ int bshift_of(int t){
  int tap = t >> 3;
  int dy = (tap * 11) >> 5;              // tap/3 for tap in [0,9)
  int dx = tap - dy * 3;
  return (((dy - 1) * 66 + (dx - 1)) << 9) + ((t & 7) << 6);
}

__global__ __launch_bounds__(512, 2) void conv_gemm(
    const unsigned short* __restrict__ wmod, const unsigned short* __restrict__ xpad,
    const float* __restrict__ noise, const float* __restrict__ bias,
    float* __restrict__ out){
  __shared__ unsigned short As[4][128 * 64];   // 64 KiB
  __shared__ unsigned short Bs[4][128 * 64];   // 64 KiB
  int g = blockIdx.x;                          // 256 blocks: 1 per CU
  int b = g & 7, sl = g >> 3;                  // b == XCD
  int mt = sl >> 4, nt = sl & 15;
  int m0 = mt * 256, n0 = nt * 256, h0 = nt * 4;
  int tid = threadIdx.x, lane = tid & 63, wid = tid >> 6;
  int wmp = wid >> 2, wnp = wid & 3;
  int lf = lane & 15, lg = lane >> 4;

  const unsigned short* wbase = wmod + ((size_t)(b * 512 + m0)) * KDIM;
  const unsigned short* xb    = xpad + (size_t)b * (66 * 66 * 512);

  // staging: u = i*512+tid -> row u>>3 (of 128), LDS chunk u&7; fetch global
  // chunk (u&7)^(row&7) so linear LDS holds the swizzled layout.
  int srow  = tid >> 3;
  int sc    = (tid & 7) ^ (srow & 7);
  int aoffg  = srow * KDIM + sc * 8;
  int boffg0 = ((h0 + 1) * 66 + srow + 1) * 512 + sc * 8;
  int boffg1 = ((h0 + 2) * 66 + srow + 1) * 512 + sc * 8;

  // frag reads: row r = base + lf, logical chunk, physical = logical^(lane&7)
  int arow[4], brow[2];
#pragma unroll
  for (int i = 0; i < 4; ++i) arow[i] = (wmp * 64 + i * 16 + lf) * 64;
#pragma unroll
  for (int j = 0; j < 2; ++j) brow[j] = (wnp * 32 + j * 16 + lf) * 64;
  int pch0 = ((lg    ) ^ (lane & 7)) * 8;
  int pch1 = ((lg + 4) ^ (lane & 7)) * 8;

  f32x4 acc[2][2][4][2];
#pragma unroll
  for (int a0 = 0; a0 < 2; ++a0)
#pragma unroll
    for (int a1 = 0; a1 < 2; ++a1)
#pragma unroll
      for (int a2 = 0; a2 < 4; ++a2)
#pragma unroll
        for (int a3 = 0; a3 < 2; ++a3) acc[a0][a1][a2][a3] = (f32x4){0.f, 0.f, 0.f, 0.f};

  bf16x8 af0[4][2], af1[4][2], bq0[2][2], bq1[2][2];

#define SBAR0() __builtin_amdgcn_sched_barrier(0)

#define STAGE_A(t_, h_, s_) do {                                              \
    const unsigned short* gpa_ = wbase + (size_t)(h_) * (128 * KDIM) + (t_) * 64; \
    GLDS16(gpa_ + aoffg,             &As[s_][tid * 8]);                       \
    GLDS16(gpa_ + aoffg + 64 * KDIM, &As[s_][(512 + tid) * 8]);               \
  } while (0)

#define STAGE_B(t_, h_, s_) do {                                              \
    const unsigned short* gpb_ = xb + (h_) * (2 * 66 * 512) + bshift_of(t_);  \
    GLDS16(gpb_ + boffg0, &Bs[s_][tid * 8]);                                  \
    GLDS16(gpb_ + boffg1, &Bs[s_][(512 + tid) * 8]);                          \
  } while (0)

#define LOAD_AF1(AF_, s_, fi_) do {                                           \
    AF_[fi_][0] = *(const bf16x8*)&As[s_][arow[fi_] + pch0];                  \
    AF_[fi_][1] = *(const bf16x8*)&As[s_][arow[fi_] + pch1];                  \
  } while (0)

#define LOAD_BQ(B_, s_) do {                                                  \
    _Pragma("unroll") for (int fj_ = 0; fj_ < 2; ++fj_){                      \
      B_[fj_][0] = *(const bf16x8*)&Bs[s_][brow[fj_] + pch0];                 \
      B_[fj_][1] = *(const bf16x8*)&Bs[s_][brow[fj_] + pch1]; }               \
  } while (0)

#define MFMA_Q(MH_, NH_, AF_, B_) do {                                        \
    __builtin_amdgcn_s_setprio(1);                                            \
    _Pragma("unroll") for (int fi_ = 0; fi_ < 4; ++fi_)                       \
    _Pragma("unroll") for (int fj_ = 0; fj_ < 2; ++fj_){                      \
      acc[MH_][NH_][fi_][fj_] = __builtin_amdgcn_mfma_f32_16x16x32_bf16(      \
          AF_[fi_][0], B_[fj_][0], acc[MH_][NH_][fi_][fj_], 0, 0, 0);         \
      acc[MH_][NH_][fi_][fj_] = __builtin_amdgcn_mfma_f32_16x16x32_bf16(      \
          AF_[fi_][1], B_[fj_][1], acc[MH_][NH_][fi_][fj_], 0, 0, 0); }       \
    __builtin_amdgcn_s_setprio(0);                                            \
  } while (0)

// head wait: current phase's 6 future-operand reads may pend; older complete.
#define TAIL6() do { SBAR0();                                                 \
    asm volatile("s_waitcnt lgkmcnt(6)" ::: "memory"); SBAR0(); } while (0)
#define TAIL0() do { SBAR0();                                                 \
    asm volatile("s_waitcnt lgkmcnt(0)" ::: "memory"); SBAR0(); } while (0)
#define PH_END() do { SBAR0(); __builtin_amdgcn_s_barrier(); } while (0)
#define VMW4() asm volatile("s_waitcnt vmcnt(4)" ::: "memory")
#define VMW0() asm volatile("s_waitcnt vmcnt(0)" ::: "memory")

  // prologue: stage tiles 0 and 1 fully (8 half-tiles), drain, preload
  // tile0 operands (af0 <- As[0], bq0 <- Bs[0]).
  STAGE_A(0, 0, 0); STAGE_A(0, 1, 1); STAGE_B(0, 0, 0); STAGE_B(0, 1, 1);
  STAGE_A(1, 0, 2); STAGE_B(1, 0, 2); STAGE_B(1, 1, 3); STAGE_A(1, 1, 3);
  VMW0();
  __builtin_amdgcn_s_barrier();
  LOAD_AF1(af0, 0, 0); LOAD_AF1(af0, 0, 1); LOAD_AF1(af0, 0, 2); LOAD_AF1(af0, 0, 3);
  LOAD_BQ(bq0, 0);

  // main loop: iter it computes tiles T=2it (Q1-Q4) and T+1 (Q5-Q8).
  // reads one phase ahead; stages Q2(A0+B0,T+2) Q3(B1) Q4(A1) Q6(A2+B2,T+3)
  // Q7(B3) Q8(A3); VMW4 at Q4/Q8.
#pragma unroll 1
  for (int it = 0; it < 35; ++it){
    int T = it * 2;
    // Q1: MFMA (0,0) of T
    LOAD_BQ(bq1, 1); LOAD_AF1(af1, 1, 0);
    TAIL6(); MFMA_Q(0, 0, af0, bq0); PH_END();
    // Q2: (0,1)
    STAGE_A(T + 2, 0, 0); STAGE_B(T + 2, 0, 0);
    LOAD_AF1(af1, 1, 1); LOAD_AF1(af1, 1, 2); LOAD_AF1(af1, 1, 3);
    TAIL6(); MFMA_Q(0, 1, af0, bq1); PH_END();
    // Q3: (1,0)
    STAGE_B(T + 2, 1, 1);
    LOAD_AF1(af0, 2, 0); LOAD_AF1(af0, 2, 1); LOAD_AF1(af0, 2, 2);
    TAIL6(); MFMA_Q(1, 0, af1, bq0); PH_END();
    // Q4: (1,1); retire Q2's stages (+older) for Q7/Q8 reads
    STAGE_A(T + 2, 1, 1);
    VMW4();
    LOAD_BQ(bq0, 2); LOAD_AF1(af0, 2, 3);
    TAIL6(); MFMA_Q(1, 1, af1, bq1); PH_END();
    // Q5: (0,0) of T+1
    LOAD_BQ(bq1, 3); LOAD_AF1(af1, 3, 0);
    TAIL6(); MFMA_Q(0, 0, af0, bq0); PH_END();
    // Q6: (0,1)
    STAGE_A(T + 3, 0, 2); STAGE_B(T + 3, 0, 2);
    LOAD_AF1(af1, 3, 1); LOAD_AF1(af1, 3, 2); LOAD_AF1(af1, 3, 3);
    TAIL6(); MFMA_Q(0, 1, af0, bq1); PH_END();
    // Q7: (1,0)
    STAGE_B(T + 3, 1, 3);
    LOAD_AF1(af0, 0, 0); LOAD_AF1(af0, 0, 1); LOAD_AF1(af0, 0, 2);
    TAIL6(); MFMA_Q(1, 0, af1, bq0); PH_END();
    // Q8: (1,1); retire Q6's stages for next-iter Q3/Q4 reads
    STAGE_A(T + 3, 1, 3);
    VMW4();
    LOAD_BQ(bq0, 0); LOAD_AF1(af0, 0, 3);
    TAIL6(); MFMA_Q(1, 1, af1, bq1); PH_END();
  }

  // epilogue iteration: tiles 70 (slots 0/1), 71 (slots 2/3); no stages;
  // VMW0 at Q4 drains the two leftover stages (Bs[3],As[3] of tile 71).
  LOAD_BQ(bq1, 1); LOAD_AF1(af1, 1, 0);
  TAIL6(); MFMA_Q(0, 0, af0, bq0); PH_END();
  LOAD_AF1(af1, 1, 1); LOAD_AF1(af1, 1, 2); LOAD_AF1(af1, 1, 3);
  TAIL6(); MFMA_Q(0, 1, af0, bq1); PH_END();
  LOAD_AF1(af0, 2, 0); LOAD_AF1(af0, 2, 1); LOAD_AF1(af0, 2, 2);
  TAIL6(); MFMA_Q(1, 0, af1, bq0); PH_END();
  VMW0();
  LOAD_BQ(bq0, 2); LOAD_AF1(af0, 2, 3);
  TAIL6(); MFMA_Q(1, 1, af1, bq1); PH_END();
  LOAD_BQ(bq1, 3); LOAD_AF1(af1, 3, 0);
  TAIL6(); MFMA_Q(0, 0, af0, bq0); PH_END();
  LOAD_AF1(af1, 3, 1); LOAD_AF1(af1, 3, 2); LOAD_AF1(af1, 3, 3);
  TAIL6(); MFMA_Q(0, 1, af0, bq1); PH_END();
  TAIL0(); MFMA_Q(1, 0, af1, bq0); PH_END();
  TAIL0(); MFMA_Q(1, 1, af1, bq1);

#undef STAGE_A
#undef STAGE_B
#undef LOAD_AF1
#undef LOAD_BQ
#undef MFMA_Q
#undef TAIL6
#undef TAIL0
#undef PH_END
#undef VMW4
#undef VMW0
#undef SBAR0

  // epilogue: + noise + bias, leaky relu 0.2. C/D map: row=(lane>>4)*4+reg,
  // col=lane&15
#pragma unroll
  for (int MH = 0; MH < 2; ++MH)
#pragma unroll
    for (int NH = 0; NH < 2; ++NH)
#pragma unroll
      for (int fi = 0; fi < 4; ++fi)
#pragma unroll
        for (int fj = 0; fj < 2; ++fj){
          int o_base = m0 + MH * 128 + wmp * 64 + fi * 16 + lg * 4;
          int n = n0 + NH * 128 + wnp * 32 + fj * 16 + lf;
#pragma unroll
          for (int r = 0; r < 4; ++r){
            int o = o_base + r;
            size_t idx = ((size_t)(b * 512 + o)) * HWPIX + n;
            float v = acc[MH][NH][fi][fj][r] + noise[idx] + bias[o];
            out[idx] = (v >= 0.f) ? v : 0.2f * v;
          }
        }
}

extern "C" void kernel_launch(void* const* d_in, const int* in_sizes, int n_in,
                              void* d_out, int out_size, void* d_ws, size_t ws_size,
                              hipStream_t stream) {
  const float* x        = (const float*)d_in[0];
  const float* w        = (const float*)d_in[1];
  const float* noise    = (const float*)d_in[2];
  const float* weight   = (const float*)d_in[3];
  const float* affine_w = (const float*)d_in[4];
  const float* affine_b = (const float*)d_in[5];
  const float* bias     = (const float*)d_in[6];
  float* out = (float*)d_out;

  // workspace: styles 16KB | wmod 37,748,736B | xpad 35,684,352B  (~73.5 MB)
  float* styles = (float*)d_ws;
  unsigned short* wmod = (unsigned short*)((char*)d_ws + 16384);
  unsigned short* xpad = (unsigned short*)((char*)d_ws + 16384 + 37748736ull);

  style_k<<<dim3(1024), 256, 0, stream>>>(w, affine_w, affine_b, styles);
  modw_k <<<dim3(512, 8), 256, 0, stream>>>(weight, styles, wmod);
  xpose_k<<<dim3(64, 8, 8), 256, 0, stream>>>(x, xpad);
  conv_gemm<<<dim3(256), 512, 0, stream>>>(wmod, xpad, noise, bias, out);
}